// Round 8
// baseline (232.479 us; speedup 1.0000x reference)
//
#include <hip/hip_runtime.h>
#include <hip/hip_bf16.h>
#include <hip/hip_cooperative_groups.h>

namespace cg = cooperative_groups;

// StochasticEnsemble: hard-routed 8-expert MLP.
// Round 17: REVERT round-16 XCD swizzle (78 us, FETCH 75->95 MB: clustering
// all n-blocks of one mt per XCD streams whole 12-MB expert panels through
// 4-MB L2s with zero reuse). gemm1/gemm2 byte-identical to round 14 (best
// measured: 203.8 total, gemm2 61). NEW: memset+route+scan fused into ONE
// cooperative kernel (per-block pcnt, grid.sync, direct perm scatter) —
// removes 2 dispatches, the bucket round-trip, and the 1-block scan kernel.
// Targets the config-invariant ~142 us outside gemm2.

#define BATCH 2048
#define ZD 128
#define HID 1024
#define OUTD 3072
#define NEXP 8
#define MAXTF 24          // max 128-row M-tiles
#define NRB (BATCH / 32)  // 64 route blocks

typedef short bf16x8 __attribute__((ext_vector_type(8)));   // 8 bf16 = 4 VGPRs
typedef float f32x4 __attribute__((ext_vector_type(4)));

// Raw barrier: LDS-write visibility (lgkmcnt 0) but NO vmcnt drain.
#define BAR_NODRAIN()                                             \
    do {                                                          \
        asm volatile("s_waitcnt lgkmcnt(0)" ::: "memory");        \
        __builtin_amdgcn_s_barrier();                             \
        asm volatile("" ::: "memory");                            \
    } while (0)

// ---- workspace byte layout (ws_size = 384 MiB) ----
// 64       ntl[1]
// 128      texp[24]
// 256      perm[3072]               -> ends 12544
// 12544    pcnt[64*8]               -> ends 14592
// 78080    zb bf16 [2048*128]       -> ends 602368
// 602368   Hb bf16 [3072*1024]      -> ends 6893824

// ---------------- fused route+scan (cooperative, 64 blocks) ----------------
__global__ __launch_bounds__(256) void routescan_kernel(
    const float* __restrict__ z, __hip_bfloat16* __restrict__ zb,
    int* __restrict__ pcnt, int* __restrict__ ntl,
    int* __restrict__ texp, int* __restrict__ perm) {
    __shared__ int lcnt[NEXP];            // phase1: local counts; phase2: totals
    __shared__ int se[32], sp[32];        // per-sample expert / local rank
    __shared__ int base_s[NEXP];          // sum of pcnt[b][e] for b < bid
    __shared__ int soff_s[NEXP + 1];

    int t = threadIdx.x, bid = blockIdx.x;
    if (t < NEXP) lcnt[t] = 0;
    __syncthreads();

    int s = bid * 32 + (t >> 3);          // sample
    int li = t & 7;                       // lane-in-sample
    const float* zp = z + (size_t)s * ZD + li * 16;
    float sum = 0.f;
    union { bf16x8 v8; __hip_bfloat16 h[8]; } u0, u1;
#pragma unroll
    for (int i = 0; i < 4; i++) {
        float4 v = ((const float4*)zp)[i];
        sum += floorf(fabsf(v.x) * 1000.0f) + floorf(fabsf(v.y) * 1000.0f) +
               floorf(fabsf(v.z) * 1000.0f) + floorf(fabsf(v.w) * 1000.0f);
        __hip_bfloat16* dst = (i < 2) ? &u0.h[i * 4] : &u1.h[(i - 2) * 4];
        dst[0] = __float2bfloat16(v.x);
        dst[1] = __float2bfloat16(v.y);
        dst[2] = __float2bfloat16(v.z);
        dst[3] = __float2bfloat16(v.w);
    }
    bf16x8* zo = (bf16x8*)(zb + (size_t)s * ZD + li * 16);
    zo[0] = u0.v8;
    zo[1] = u1.v8;

    sum += __shfl_down(sum, 4);
    sum += __shfl_down(sum, 2);
    sum += __shfl_down(sum, 1);
    if (li == 0) {
        int e = ((int)sum) & 7;
        int lpos = atomicAdd(&lcnt[e], 1);
        se[t >> 3] = e;
        sp[t >> 3] = lpos;
    }
    __syncthreads();
    if (t < NEXP) pcnt[bid * NEXP + t] = lcnt[t];

    cg::this_grid().sync();

    // totals (all blocks) + my-block prefix per expert
    if (t < NEXP) {
        int tot = 0, pre = 0;
#pragma unroll 1
        for (int b = 0; b < NRB; ++b) {
            int c = pcnt[b * NEXP + t];
            if (b < bid) pre += c;
            tot += c;
        }
        lcnt[t] = tot;          // phase1 lcnt no longer needed
        base_s[t] = pre;
    }
    __syncthreads();
    if (t == 0) {
        int o = 0;
        for (int e = 0; e < NEXP; e++) {
            soff_s[e] = o;
            o += (lcnt[e] + 127) & ~127;
        }
        soff_s[NEXP] = o;
    }
    __syncthreads();

    // scatter my 32 samples directly into perm
    if (t < 32) {
        int e = se[t];
        perm[soff_s[e] + base_s[e] + sp[t]] = bid * 32 + t;
    }

    // block 0: pads, texp, ntl
    if (bid == 0) {
        int total = soff_s[NEXP];
        if (t == 0) *ntl = total / 128;
        for (int tt = t; tt < total / 128; tt += 256) {
            int r = tt * 128, e = 0;
            while (r >= soff_s[e + 1]) e++;
            texp[tt] = e;
        }
        for (int r = t; r < total; r += 256) {
            int e = 0;
            while (r >= soff_s[e + 1]) e++;
            if (r - soff_s[e] >= lcnt[e]) perm[r] = -1;
        }
    }
}

// ---------------- gemm1: 64m x 64n, BK=64, K=128 (2 iters) ----------------
// ~608 blocks. All-thread staging; dbuf; 1 raw barrier/iter; XOR-chunk LDS.
__global__ __launch_bounds__(256, 4) void gemm1_fast(
    const __hip_bfloat16* __restrict__ zb, const float* __restrict__ W1,
    const float* __restrict__ b1, const int* __restrict__ ntl,
    const int* __restrict__ texp, const int* __restrict__ perm,
    __hip_bfloat16* __restrict__ H) {
    int mt = blockIdx.y;                 // 64-row tile index
    if (mt >= 2 * (*ntl)) return;
    int e = texp[mt >> 1];
    int n0 = blockIdx.x * 64;

    __shared__ __align__(16) __hip_bfloat16 As[2][64 * 64];   // 2 x 8 KB
    __shared__ __align__(16) __hip_bfloat16 Bs[2][64 * 64];   // 2 x 8 KB

    int tid = threadIdx.x;
    int lane = tid & 63, wave = tid >> 6;
    int cc = lane & 15, q = lane >> 4;
    int mw = (wave >> 1) * 32, nw = (wave & 1) * 32;

    // A staging: thread t covers rows rg and rg+32, k-chunk sc
    int sc = tid & 7, rg = tid >> 3;     // rg 0..31
    int r0 = perm[mt * 64 + rg];      if (r0 < 0) r0 = 0;
    int r1 = perm[mt * 64 + rg + 32]; if (r1 < 0) r1 = 0;
    const __hip_bfloat16* Ap0 = zb + (size_t)r0 * ZD + sc * 8;
    const __hip_bfloat16* Ap1 = zb + (size_t)r1 * ZD + sc * 8;
    int awb = rg * 64 + (sc ^ (rg & 7)) * 8;   // row rg+32 -> +2048, same xor

    // B staging: bkc = k-chunk, 2 n per thread (float2 loads, 64B segments)
    int bkc = tid & 7, bn2 = (tid >> 3) * 2;   // bn2 0..62
    const float* Bgf = W1 + (size_t)e * ZD * HID + (size_t)(bkc * 8) * HID + n0 + bn2;
    int bwb[2];
#pragma unroll
    for (int j = 0; j < 2; j++)
        bwb[j] = ((bn2 + j) * 8 + (bkc ^ ((bn2 + j) & 7))) * 8;

    int A0 = (mw + cc) * 64, B0 = (nw + cc) * 64;
    int X0 = (q ^ (cc & 7)) * 8, X1 = ((4 + q) ^ (cc & 7)) * 8;

    float bias[2];
#pragma unroll
    for (int j = 0; j < 2; j++) bias[j] = b1[(size_t)e * HID + n0 + nw + j * 16 + cc];

    f32x4 zero4 = {0.f, 0.f, 0.f, 0.f};
    f32x4 acc[2][2];
#pragma unroll
    for (int i = 0; i < 2; i++)
#pragma unroll
        for (int j = 0; j < 2; j++) acc[i][j] = zero4;

    bf16x8 ga0 = *(const bf16x8*)Ap0;
    bf16x8 ga1 = *(const bf16x8*)Ap1;
    float2 braw[8];
#pragma unroll
    for (int i = 0; i < 8; i++) braw[i] = *(const float2*)(Bgf + (size_t)i * HID);

#pragma unroll
    for (int it = 0; it < 2; ++it) {
        __hip_bfloat16* Ac = As[it];
        __hip_bfloat16* Bc = Bs[it];
        union { bf16x8 v8; __hip_bfloat16 h[8]; } gbv[2];
#pragma unroll
        for (int i = 0; i < 8; i++) {
            gbv[0].h[i] = __float2bfloat16(braw[i].x);
            gbv[1].h[i] = __float2bfloat16(braw[i].y);
        }
        *(bf16x8*)(Ac + awb) = ga0;
        *(bf16x8*)(Ac + awb + 2048) = ga1;
#pragma unroll
        for (int j = 0; j < 2; j++) *(bf16x8*)(Bc + bwb[j]) = gbv[j].v8;
        if (it == 0) {
            ga0 = *(const bf16x8*)(Ap0 + 64);
            ga1 = *(const bf16x8*)(Ap1 + 64);
#pragma unroll
            for (int i = 0; i < 8; i++)
                braw[i] = *(const float2*)(Bgf + (size_t)(64 + i) * HID);
        }
        BAR_NODRAIN();
#pragma unroll
        for (int kh = 0; kh < 2; ++kh) {
            int X = kh ? X1 : X0;
            bf16x8 af[2], bfr[2];
#pragma unroll
            for (int i = 0; i < 2; i++) af[i] = *(const bf16x8*)(Ac + A0 + i * 1024 + X);
#pragma unroll
            for (int j = 0; j < 2; j++) bfr[j] = *(const bf16x8*)(Bc + B0 + j * 1024 + X);
#pragma unroll
            for (int i = 0; i < 2; i++)
#pragma unroll
                for (int j = 0; j < 2; j++)
                    acc[i][j] = __builtin_amdgcn_mfma_f32_16x16x32_bf16(af[i], bfr[j],
                                                                        acc[i][j], 0, 0, 0);
        }
    }
#pragma unroll
    for (int i = 0; i < 2; i++)
#pragma unroll
        for (int r = 0; r < 4; r++) {
            int m = mw + i * 16 + q * 4 + r;
            __hip_bfloat16* hp = H + (size_t)(mt * 64 + m) * HID + n0 + nw + cc;
#pragma unroll
            for (int j = 0; j < 2; j++)
                hp[j * 16] = __float2bfloat16(fmaxf(acc[i][j][r] + bias[j], 0.f));
        }
}

// ---------------- gemm2: 128m x 128n, BK=64 (round-6 geometry) ----------------
// Grid (24, MAXTF) = 576 blocks, 2 blocks/CU (64.5 KB LDS). All-thread staging,
// convert deferred past the MFMA phase, ONE raw barrier per phase, 2 LDS
// buffers, distance-2 register prefetch (sets A/B).
__global__ __launch_bounds__(256, 2) void gemm2_fast(
    const __hip_bfloat16* __restrict__ H, const float* __restrict__ W2,
    const float* __restrict__ b2, const int* __restrict__ ntl,
    const int* __restrict__ texp, const int* __restrict__ perm,
    float* __restrict__ out) {
    int mt = blockIdx.y;
    if (mt >= *ntl) return;
    int e = texp[mt];
    int n0 = blockIdx.x * 128;

    __shared__ __align__(16) __hip_bfloat16 As[2][128 * 64];   // 2 x 16 KB
    __shared__ __align__(16) __hip_bfloat16 Bs[2][128 * 64];   // 2 x 16 KB
    __shared__ int rows_s[128];

    int tid = threadIdx.x;
    if (tid < 128) rows_s[tid] = perm[mt * 128 + tid];

    int lane = tid & 63, wave = tid >> 6;
    int cc = lane & 15, q = lane >> 4;
    int mw = (wave >> 1) * 64, nw = (wave & 1) * 64;

    // A staging: thread covers rows sr + p*32 (p=0..3), k-chunk sc
    int sr = tid >> 3, sc = tid & 7;
    int awbase = sr * 64 + (sc ^ (sr & 7)) * 8;     // + p*2048
    const __hip_bfloat16* Ag = H + ((size_t)mt * 128 + sr) * HID + sc * 8;

    // B staging: bkc = k-chunk (8 rows), 4 n per thread (float4)
    int bkc = tid & 7, bn = (tid >> 3) * 4;
    const float* Bgf = W2 + (size_t)e * HID * OUTD + (size_t)(bkc * 8) * OUTD + n0 + bn;
    int bwb[4];
#pragma unroll
    for (int j = 0; j < 4; j++)
        bwb[j] = (bn + j) * 64 + ((bkc ^ ((bn + j) & 7))) * 8;

    int A0 = (mw + cc) * 64, B0 = (nw + cc) * 64;
    int X0 = (q ^ (cc & 7)) * 8, X1 = ((4 + q) ^ (cc & 7)) * 8;

    float bias[4];
#pragma unroll
    for (int j = 0; j < 4; j++) bias[j] = b2[(size_t)e * OUTD + n0 + nw + j * 16 + cc];

    f32x4 zero4 = {0.f, 0.f, 0.f, 0.f};
    f32x4 acc[4][4];
#pragma unroll
    for (int i = 0; i < 4; i++)
#pragma unroll
        for (int j = 0; j < 4; j++) acc[i][j] = zero4;

    // Distance-2 prefetch: set A holds k-block (2*itp), set B holds (2*itp+1).
    bf16x8 gaA[4], gaB[4];
    float4 brA[8], brB[8];
#pragma unroll
    for (int p = 0; p < 4; p++) gaA[p] = *(const bf16x8*)(Ag + (size_t)p * 32 * HID);
#pragma unroll
    for (int i = 0; i < 8; i++) brA[i] = *(const float4*)(Bgf + (size_t)i * OUTD);
#pragma unroll
    for (int p = 0; p < 4; p++) gaB[p] = *(const bf16x8*)(Ag + (size_t)p * 32 * HID + 64);
#pragma unroll
    for (int i = 0; i < 8; i++) brB[i] = *(const float4*)(Bgf + (size_t)(64 + i) * OUTD);

    const int NIT = HID / 64;   // 16 (even)
    for (int itp = 0; itp < NIT / 2; ++itp) {
        int kre = itp * 128;                 // reload bases: even -> kre+128, odd -> kre+192
        bool more = (itp < NIT / 2 - 1);

        // ======== even iter (k-block 2*itp): consume set A, LDS buf 0 ========
        {
            union { bf16x8 v8; __hip_bfloat16 h[8]; } gb[4];
#pragma unroll
            for (int i = 0; i < 8; i++) {
                gb[0].h[i] = __float2bfloat16(brA[i].x);
                gb[1].h[i] = __float2bfloat16(brA[i].y);
                gb[2].h[i] = __float2bfloat16(brA[i].z);
                gb[3].h[i] = __float2bfloat16(brA[i].w);
            }
#pragma unroll
            for (int p = 0; p < 4; p++) *(bf16x8*)(As[0] + awbase + p * 2048) = gaA[p];
#pragma unroll
            for (int j = 0; j < 4; j++) *(bf16x8*)(Bs[0] + bwb[j]) = gb[j].v8;
            if (more) {
#pragma unroll
                for (int p = 0; p < 4; p++)
                    gaA[p] = *(const bf16x8*)(Ag + (size_t)p * 32 * HID + kre + 128);
#pragma unroll
                for (int i = 0; i < 8; i++)
                    brA[i] = *(const float4*)(Bgf + (size_t)(kre + 128 + i) * OUTD);
            }
            BAR_NODRAIN();
#pragma unroll
            for (int kh = 0; kh < 2; ++kh) {
                int X = kh ? X1 : X0;
                bf16x8 af[4], bfr[4];
#pragma unroll
                for (int i = 0; i < 4; i++) af[i] = *(const bf16x8*)(As[0] + A0 + i * 1024 + X);
#pragma unroll
                for (int j = 0; j < 4; j++) bfr[j] = *(const bf16x8*)(Bs[0] + B0 + j * 1024 + X);
#pragma unroll
                for (int i = 0; i < 4; i++)
#pragma unroll
                    for (int j = 0; j < 4; j++)
                        acc[i][j] = __builtin_amdgcn_mfma_f32_16x16x32_bf16(af[i], bfr[j],
                                                                            acc[i][j], 0, 0, 0);
            }
        }

        // ======== odd iter (k-block 2*itp+1): consume set B, LDS buf 1 ========
        {
            union { bf16x8 v8; __hip_bfloat16 h[8]; } gb[4];
#pragma unroll
            for (int i = 0; i < 8; i++) {
                gb[0].h[i] = __float2bfloat16(brB[i].x);
                gb[1].h[i] = __float2bfloat16(brB[i].y);
                gb[2].h[i] = __float2bfloat16(brB[i].z);
                gb[3].h[i] = __float2bfloat16(brB[i].w);
            }
#pragma unroll
            for (int p = 0; p < 4; p++) *(bf16x8*)(As[1] + awbase + p * 2048) = gaB[p];
#pragma unroll
            for (int j = 0; j < 4; j++) *(bf16x8*)(Bs[1] + bwb[j]) = gb[j].v8;
            if (more) {
#pragma unroll
                for (int p = 0; p < 4; p++)
                    gaB[p] = *(const bf16x8*)(Ag + (size_t)p * 32 * HID + kre + 192);
#pragma unroll
                for (int i = 0; i < 8; i++)
                    brB[i] = *(const float4*)(Bgf + (size_t)(kre + 192 + i) * OUTD);
            }
            BAR_NODRAIN();
#pragma unroll
            for (int kh = 0; kh < 2; ++kh) {
                int X = kh ? X1 : X0;
                bf16x8 af[4], bfr[4];
#pragma unroll
                for (int i = 0; i < 4; i++) af[i] = *(const bf16x8*)(As[1] + A0 + i * 1024 + X);
#pragma unroll
                for (int j = 0; j < 4; j++) bfr[j] = *(const bf16x8*)(Bs[1] + B0 + j * 1024 + X);
#pragma unroll
                for (int i = 0; i < 4; i++)
#pragma unroll
                    for (int j = 0; j < 4; j++)
                        acc[i][j] = __builtin_amdgcn_mfma_f32_16x16x32_bf16(af[i], bfr[j],
                                                                            acc[i][j], 0, 0, 0);
            }
        }
    }

#pragma unroll
    for (int i = 0; i < 4; i++)
#pragma unroll
        for (int r = 0; r < 4; r++) {
            int m = mw + i * 16 + q * 4 + r;
            int orow = rows_s[m];
            if (orow >= 0) {
                float* op = out + (size_t)orow * OUTD + n0 + nw + cc;
#pragma unroll
                for (int j = 0; j < 4; j++) op[j * 16] = acc[i][j][r] + bias[j];
            }
        }
}

extern "C" void kernel_launch(void* const* d_in, const int* in_sizes, int n_in,
                              void* d_out, int out_size, void* d_ws, size_t ws_size,
                              hipStream_t stream) {
    const float* z  = (const float*)d_in[0];
    const float* W1 = (const float*)d_in[1];
    const float* b1 = (const float*)d_in[2];
    const float* W2 = (const float*)d_in[3];
    const float* b2 = (const float*)d_in[4];
    float* out = (float*)d_out;

    char* ws = (char*)d_ws;
    int* ntl    = (int*)(ws + 64);
    int* texp   = (int*)(ws + 128);
    int* perm   = (int*)(ws + 256);
    int* pcnt   = (int*)(ws + 12544);
    __hip_bfloat16* zb  = (__hip_bfloat16*)(ws + 78080);
    __hip_bfloat16* Hb  = (__hip_bfloat16*)(ws + 602368);

    void* kargs[] = {(void*)&z, (void*)&zb, (void*)&pcnt,
                     (void*)&ntl, (void*)&texp, (void*)&perm};
    hipLaunchCooperativeKernel((const void*)routescan_kernel, dim3(NRB), dim3(256),
                               kargs, 0, stream);
    hipLaunchKernelGGL(gemm1_fast, dim3(HID / 64, 2 * MAXTF), dim3(256), 0, stream,
                       zb, W1, b1, ntl, texp, perm, Hb);
    hipLaunchKernelGGL(gemm2_fast, dim3(OUTD / 128, MAXTF), dim3(256), 0, stream,
                       Hb, W2, b2, ntl, texp, perm, out);
}

// Round 9
// 209.912 us; speedup vs baseline: 1.1075x; 1.1075x over previous
//
#include <hip/hip_runtime.h>
#include <hip/hip_bf16.h>

// StochasticEnsemble: hard-routed 8-expert MLP.
// Round 18: REVERT round-17 coop fusion (+28.7 us launch cost). Back to the
// 5-dispatch round-14 pipeline. ONE change: gemm2 BK 64 -> 128 (8 phases
// instead of 16, same 576-block grid, same total bytes). Evidence from r10-r17:
// gemm2 time ~ (phase-slots) x ~2.3us with a fixed per-phase overhead
// (m233-style stage+barrier cost); content, prefetch depth, occupancy and
// locality are all null levers. Halving phase count is the only untested
// corner. LDS 98.5 KB -> 1 block/CU (r15 showed occupancy is not the lever).

#define BATCH 2048
#define ZD 128
#define HID 1024
#define OUTD 3072
#define NEXP 8
#define MAXTF 24          // max 128-row M-tiles

typedef short bf16x8 __attribute__((ext_vector_type(8)));   // 8 bf16 = 4 VGPRs
typedef float f32x4 __attribute__((ext_vector_type(4)));

// Raw barrier: LDS-write visibility (lgkmcnt 0) but NO vmcnt drain.
#define BAR_NODRAIN()                                             \
    do {                                                          \
        asm volatile("s_waitcnt lgkmcnt(0)" ::: "memory");        \
        __builtin_amdgcn_s_barrier();                             \
        asm volatile("" ::: "memory");                            \
    } while (0)

// ---- workspace byte layout (ws_size = 384 MiB) ----
// 0        counts[8]
// 64       ntl[1]
// 128      texp[24]
// 256      perm[3072]               -> ends 12544
// 12544    bucket[8*2048]           -> ends 78080
// 78080    zb bf16 [2048*128]       -> ends 602368
// 602368   Hb bf16 [3072*1024]      -> ends 6893824

__global__ __launch_bounds__(256) void route_kernel(const float* __restrict__ z,
                                                    __hip_bfloat16* __restrict__ zb,
                                                    int* counts, int* bucket) {
    __shared__ int lcnt[NEXP];
    __shared__ int gbase[NEXP];
    int t = threadIdx.x;
    if (t < NEXP) lcnt[t] = 0;
    __syncthreads();

    int s = blockIdx.x * 32 + (t >> 3);          // sample
    int li = t & 7;                               // lane-in-sample
    const float* zp = z + (size_t)s * ZD + li * 16;
    float sum = 0.f;
    union { bf16x8 v8; __hip_bfloat16 h[8]; } u0, u1;
#pragma unroll
    for (int i = 0; i < 4; i++) {
        float4 v = ((const float4*)zp)[i];
        sum += floorf(fabsf(v.x) * 1000.0f) + floorf(fabsf(v.y) * 1000.0f) +
               floorf(fabsf(v.z) * 1000.0f) + floorf(fabsf(v.w) * 1000.0f);
        __hip_bfloat16* dst = (i < 2) ? &u0.h[i * 4] : &u1.h[(i - 2) * 4];
        dst[0] = __float2bfloat16(v.x);
        dst[1] = __float2bfloat16(v.y);
        dst[2] = __float2bfloat16(v.z);
        dst[3] = __float2bfloat16(v.w);
    }
    bf16x8* zo = (bf16x8*)(zb + (size_t)s * ZD + li * 16);
    zo[0] = u0.v8;
    zo[1] = u1.v8;

    sum += __shfl_down(sum, 4);
    sum += __shfl_down(sum, 2);
    sum += __shfl_down(sum, 1);
    int e = 0, lpos = 0;
    if (li == 0) {
        e = ((int)sum) & 7;
        lpos = atomicAdd(&lcnt[e], 1);
    }
    __syncthreads();
    if (t < NEXP) gbase[t] = atomicAdd(&counts[t], lcnt[t]);
    __syncthreads();
    if (li == 0) bucket[e * BATCH + gbase[e] + lpos] = s;
}

__global__ void scan_kernel(const int* __restrict__ counts, int* ntl,
                            int* texp, int* perm, const int* __restrict__ bucket) {
    __shared__ int soff[NEXP + 1];
    __shared__ int scnt[NEXP];
    if (threadIdx.x == 0) {
        int o = 0;
        for (int e = 0; e < NEXP; e++) {
            scnt[e] = counts[e];
            soff[e] = o;
            o += (scnt[e] + 127) & ~127;
        }
        soff[NEXP] = o;
        *ntl = o / 128;
    }
    __syncthreads();
    int total = soff[NEXP];
    for (int r = threadIdx.x; r < total; r += blockDim.x) {
        int e = 0;
        while (r >= soff[e + 1]) e++;
        int i = r - soff[e];
        perm[r] = (i < scnt[e]) ? bucket[e * BATCH + i] : -1;
        if ((r & 127) == 0) texp[r / 128] = e;
    }
}

// ---------------- gemm1: 64m x 64n, BK=64, K=128 (2 iters) ----------------
// ~608 blocks. All-thread staging; dbuf; 1 raw barrier/iter; XOR-chunk LDS.
__global__ __launch_bounds__(256, 4) void gemm1_fast(
    const __hip_bfloat16* __restrict__ zb, const float* __restrict__ W1,
    const float* __restrict__ b1, const int* __restrict__ ntl,
    const int* __restrict__ texp, const int* __restrict__ perm,
    __hip_bfloat16* __restrict__ H) {
    int mt = blockIdx.y;                 // 64-row tile index
    if (mt >= 2 * (*ntl)) return;
    int e = texp[mt >> 1];
    int n0 = blockIdx.x * 64;

    __shared__ __align__(16) __hip_bfloat16 As[2][64 * 64];   // 2 x 8 KB
    __shared__ __align__(16) __hip_bfloat16 Bs[2][64 * 64];   // 2 x 8 KB

    int tid = threadIdx.x;
    int lane = tid & 63, wave = tid >> 6;
    int cc = lane & 15, q = lane >> 4;
    int mw = (wave >> 1) * 32, nw = (wave & 1) * 32;

    // A staging: thread t covers rows rg and rg+32, k-chunk sc
    int sc = tid & 7, rg = tid >> 3;     // rg 0..31
    int r0 = perm[mt * 64 + rg];      if (r0 < 0) r0 = 0;
    int r1 = perm[mt * 64 + rg + 32]; if (r1 < 0) r1 = 0;
    const __hip_bfloat16* Ap0 = zb + (size_t)r0 * ZD + sc * 8;
    const __hip_bfloat16* Ap1 = zb + (size_t)r1 * ZD + sc * 8;
    int awb = rg * 64 + (sc ^ (rg & 7)) * 8;   // row rg+32 -> +2048, same xor

    // B staging: bkc = k-chunk, 2 n per thread (float2 loads, 64B segments)
    int bkc = tid & 7, bn2 = (tid >> 3) * 2;   // bn2 0..62
    const float* Bgf = W1 + (size_t)e * ZD * HID + (size_t)(bkc * 8) * HID + n0 + bn2;
    int bwb[2];
#pragma unroll
    for (int j = 0; j < 2; j++)
        bwb[j] = ((bn2 + j) * 8 + (bkc ^ ((bn2 + j) & 7))) * 8;

    int A0 = (mw + cc) * 64, B0 = (nw + cc) * 64;
    int X0 = (q ^ (cc & 7)) * 8, X1 = ((4 + q) ^ (cc & 7)) * 8;

    float bias[2];
#pragma unroll
    for (int j = 0; j < 2; j++) bias[j] = b1[(size_t)e * HID + n0 + nw + j * 16 + cc];

    f32x4 zero4 = {0.f, 0.f, 0.f, 0.f};
    f32x4 acc[2][2];
#pragma unroll
    for (int i = 0; i < 2; i++)
#pragma unroll
        for (int j = 0; j < 2; j++) acc[i][j] = zero4;

    bf16x8 ga0 = *(const bf16x8*)Ap0;
    bf16x8 ga1 = *(const bf16x8*)Ap1;
    float2 braw[8];
#pragma unroll
    for (int i = 0; i < 8; i++) braw[i] = *(const float2*)(Bgf + (size_t)i * HID);

#pragma unroll
    for (int it = 0; it < 2; ++it) {
        __hip_bfloat16* Ac = As[it];
        __hip_bfloat16* Bc = Bs[it];
        union { bf16x8 v8; __hip_bfloat16 h[8]; } gbv[2];
#pragma unroll
        for (int i = 0; i < 8; i++) {
            gbv[0].h[i] = __float2bfloat16(braw[i].x);
            gbv[1].h[i] = __float2bfloat16(braw[i].y);
        }
        *(bf16x8*)(Ac + awb) = ga0;
        *(bf16x8*)(Ac + awb + 2048) = ga1;
#pragma unroll
        for (int j = 0; j < 2; j++) *(bf16x8*)(Bc + bwb[j]) = gbv[j].v8;
        if (it == 0) {
            ga0 = *(const bf16x8*)(Ap0 + 64);
            ga1 = *(const bf16x8*)(Ap1 + 64);
#pragma unroll
            for (int i = 0; i < 8; i++)
                braw[i] = *(const float2*)(Bgf + (size_t)(64 + i) * HID);
        }
        BAR_NODRAIN();
#pragma unroll
        for (int kh = 0; kh < 2; ++kh) {
            int X = kh ? X1 : X0;
            bf16x8 af[2], bfr[2];
#pragma unroll
            for (int i = 0; i < 2; i++) af[i] = *(const bf16x8*)(Ac + A0 + i * 1024 + X);
#pragma unroll
            for (int j = 0; j < 2; j++) bfr[j] = *(const bf16x8*)(Bc + B0 + j * 1024 + X);
#pragma unroll
            for (int i = 0; i < 2; i++)
#pragma unroll
                for (int j = 0; j < 2; j++)
                    acc[i][j] = __builtin_amdgcn_mfma_f32_16x16x32_bf16(af[i], bfr[j],
                                                                        acc[i][j], 0, 0, 0);
        }
    }
#pragma unroll
    for (int i = 0; i < 2; i++)
#pragma unroll
        for (int r = 0; r < 4; r++) {
            int m = mw + i * 16 + q * 4 + r;
            __hip_bfloat16* hp = H + (size_t)(mt * 64 + m) * HID + n0 + nw + cc;
#pragma unroll
            for (int j = 0; j < 2; j++)
                hp[j * 16] = __float2bfloat16(fmaxf(acc[i][j][r] + bias[j], 0.f));
        }
}

// ---------------- gemm2: 128m x 128n, BK=128 (8 phases) ----------------
// Grid (24, MAXTF) = 576 blocks. LDS 98.5 KB -> 1 block/CU. All-thread
// staging (A: 8 bf16x8, B: 16 float4 per thread per phase), dist-1 register
// prefetch, converts deferred, ONE raw barrier per phase, 2 LDS buffers.
// Per-row layout: [row][k 0..127] with XOR-chunk swizzle per 64-k half.
__global__ __launch_bounds__(256) void gemm2_fast(
    const __hip_bfloat16* __restrict__ H, const float* __restrict__ W2,
    const float* __restrict__ b2, const int* __restrict__ ntl,
    const int* __restrict__ texp, const int* __restrict__ perm,
    float* __restrict__ out) {
    int mt = blockIdx.y;
    if (mt >= *ntl) return;
    int e = texp[mt];
    int n0 = blockIdx.x * 128;

    __shared__ __align__(16) __hip_bfloat16 As[2][128 * 128];   // 2 x 32 KB
    __shared__ __align__(16) __hip_bfloat16 Bs[2][128 * 128];   // 2 x 32 KB
    __shared__ int rows_s[128];

    int tid = threadIdx.x;
    if (tid < 128) rows_s[tid] = perm[mt * 128 + tid];

    int lane = tid & 63, wave = tid >> 6;
    int cc = lane & 15, q = lane >> 4;
    int mw = (wave >> 1) * 64, nw = (wave & 1) * 64;

    // A staging: rows sr + p*32 (p=0..3), chunk sc, two 64-k halves (h)
    int sr = tid >> 3, sc = tid & 7;
    int awbase = sr * 128 + (sc ^ (sr & 7)) * 8;    // + p*4096, + h*64
    const __hip_bfloat16* Ag = H + ((size_t)mt * 128 + sr) * HID + sc * 8;

    // B staging: k-chunk bkc (8 rows per half), 4 n per thread (float4)
    int bkc = tid & 7, bn = (tid >> 3) * 4;
    const float* Bgf = W2 + (size_t)e * HID * OUTD + (size_t)(bkc * 8) * OUTD + n0 + bn;
    int bwb[4];
#pragma unroll
    for (int j = 0; j < 4; j++)
        bwb[j] = (bn + j) * 128 + ((bkc ^ ((bn + j) & 7))) * 8;   // + h*64

    int A0 = (mw + cc) * 128, B0 = (nw + cc) * 128;

    float bias[4];
#pragma unroll
    for (int j = 0; j < 4; j++) bias[j] = b2[(size_t)e * OUTD + n0 + nw + j * 16 + cc];

    f32x4 zero4 = {0.f, 0.f, 0.f, 0.f};
    f32x4 acc[4][4];
#pragma unroll
    for (int i = 0; i < 4; i++)
#pragma unroll
        for (int j = 0; j < 4; j++) acc[i][j] = zero4;

    bf16x8 ga[8];        // [p*2+h]
    float4 braw[16];     // [h*8+i]
#pragma unroll
    for (int p = 0; p < 4; p++)
#pragma unroll
        for (int h = 0; h < 2; h++)
            ga[p * 2 + h] = *(const bf16x8*)(Ag + (size_t)p * 32 * HID + h * 64);
#pragma unroll
    for (int i = 0; i < 8; i++) {
        braw[i]     = *(const float4*)(Bgf + (size_t)i * OUTD);
        braw[8 + i] = *(const float4*)(Bgf + (size_t)(64 + i) * OUTD);
    }

    const int NIT = HID / 128;   // 8
    for (int it = 0; it < NIT; ++it) {
        __hip_bfloat16* Ac = As[it & 1];
        __hip_bfloat16* Bc = Bs[it & 1];
#pragma unroll
        for (int h = 0; h < 2; h++) {
            union { bf16x8 v8; __hip_bfloat16 hh[8]; } gb[4];
#pragma unroll
            for (int i = 0; i < 8; i++) {
                float4 v = braw[h * 8 + i];
                gb[0].hh[i] = __float2bfloat16(v.x);
                gb[1].hh[i] = __float2bfloat16(v.y);
                gb[2].hh[i] = __float2bfloat16(v.z);
                gb[3].hh[i] = __float2bfloat16(v.w);
            }
#pragma unroll
            for (int j = 0; j < 4; j++)
                *(bf16x8*)(Bc + bwb[j] + h * 64) = gb[j].v8;
        }
#pragma unroll
        for (int p = 0; p < 4; p++)
#pragma unroll
            for (int h = 0; h < 2; h++)
                *(bf16x8*)(Ac + awbase + p * 4096 + h * 64) = ga[p * 2 + h];
        if (it + 1 < NIT) {
            int k1 = (it + 1) * 128;
#pragma unroll
            for (int p = 0; p < 4; p++)
#pragma unroll
                for (int h = 0; h < 2; h++)
                    ga[p * 2 + h] = *(const bf16x8*)(Ag + (size_t)p * 32 * HID + k1 + h * 64);
#pragma unroll
            for (int i = 0; i < 8; i++) {
                braw[i]     = *(const float4*)(Bgf + (size_t)(k1 + i) * OUTD);
                braw[8 + i] = *(const float4*)(Bgf + (size_t)(k1 + 64 + i) * OUTD);
            }
        }
        BAR_NODRAIN();
#pragma unroll
        for (int kh = 0; kh < 4; ++kh) {
            int X = ((((kh & 1) * 4 + q) ^ (cc & 7)) * 8) + (kh >> 1) * 64;
            bf16x8 af[4], bfr[4];
#pragma unroll
            for (int i = 0; i < 4; i++) af[i] = *(const bf16x8*)(Ac + A0 + i * 2048 + X);
#pragma unroll
            for (int j = 0; j < 4; j++) bfr[j] = *(const bf16x8*)(Bc + B0 + j * 2048 + X);
#pragma unroll
            for (int i = 0; i < 4; i++)
#pragma unroll
                for (int j = 0; j < 4; j++)
                    acc[i][j] = __builtin_amdgcn_mfma_f32_16x16x32_bf16(af[i], bfr[j],
                                                                        acc[i][j], 0, 0, 0);
        }
    }

#pragma unroll
    for (int i = 0; i < 4; i++)
#pragma unroll
        for (int r = 0; r < 4; r++) {
            int m = mw + i * 16 + q * 4 + r;
            int orow = rows_s[m];
            if (orow >= 0) {
                float* op = out + (size_t)orow * OUTD + n0 + nw + cc;
#pragma unroll
                for (int j = 0; j < 4; j++) op[j * 16] = acc[i][j][r] + bias[j];
            }
        }
}

extern "C" void kernel_launch(void* const* d_in, const int* in_sizes, int n_in,
                              void* d_out, int out_size, void* d_ws, size_t ws_size,
                              hipStream_t stream) {
    const float* z  = (const float*)d_in[0];
    const float* W1 = (const float*)d_in[1];
    const float* b1 = (const float*)d_in[2];
    const float* W2 = (const float*)d_in[3];
    const float* b2 = (const float*)d_in[4];
    float* out = (float*)d_out;

    char* ws = (char*)d_ws;
    int* counts = (int*)ws;
    int* ntl    = (int*)(ws + 64);
    int* texp   = (int*)(ws + 128);
    int* perm   = (int*)(ws + 256);
    int* bucket = (int*)(ws + 12544);
    __hip_bfloat16* zb  = (__hip_bfloat16*)(ws + 78080);
    __hip_bfloat16* Hb  = (__hip_bfloat16*)(ws + 602368);

    hipMemsetAsync(counts, 0, 64, stream);
    hipLaunchKernelGGL(route_kernel, dim3(BATCH / 32), dim3(256), 0, stream,
                       z, zb, counts, bucket);
    hipLaunchKernelGGL(scan_kernel, dim3(1), dim3(256), 0, stream,
                       counts, ntl, texp, perm, bucket);
    hipLaunchKernelGGL(gemm1_fast, dim3(HID / 64, 2 * MAXTF), dim3(256), 0, stream,
                       zb, W1, b1, ntl, texp, perm, Hb);
    hipLaunchKernelGGL(gemm2_fast, dim3(OUTD / 128, MAXTF), dim3(256), 0, stream,
                       Hb, W2, b2, ntl, texp, perm, out);
}

// Round 10
// 202.073 us; speedup vs baseline: 1.1505x; 1.0388x over previous
//
#include <hip/hip_runtime.h>
#include <hip/hip_bf16.h>

// StochasticEnsemble: hard-routed 8-expert MLP.
// Round 19: gemm2 restored to round-14 form (61 us; BK=128 regressed to 68 —
// gemm2 tuning CLOSED). New: dispatches 5 -> 3. route+scan fused via
// last-block-done (device atomicAdd + threadfence, NOT cooperative launch —
// r17 showed coop costs ~30 us). Memset eliminated: done-counter needs no
// reset (exactly one of any 64 consecutive increments is == 0 mod 64, even
// from a poisoned start). bucket round-trip replaced by per-sample packed
// (e,lpos) + per-block counts, scattered by the last block.
// Targets the config-invariant ~141.5 us outside gemm2.

#define BATCH 2048
#define ZD 128
#define HID 1024
#define OUTD 3072
#define NEXP 8
#define MAXTF 24          // max 128-row M-tiles
#define NRB (BATCH / 32)  // 64 route blocks

typedef short bf16x8 __attribute__((ext_vector_type(8)));   // 8 bf16 = 4 VGPRs
typedef float f32x4 __attribute__((ext_vector_type(4)));

// Raw barrier: LDS-write visibility (lgkmcnt 0) but NO vmcnt drain.
#define BAR_NODRAIN()                                             \
    do {                                                          \
        asm volatile("s_waitcnt lgkmcnt(0)" ::: "memory");        \
        __builtin_amdgcn_s_barrier();                             \
        asm volatile("" ::: "memory");                            \
    } while (0)

// ---- workspace byte layout (ws_size = 384 MiB) ----
// 0        done[1]   (monotonic, never reset)
// 64       ntl[1]
// 128      texp[24]
// 256      perm[3072]               -> ends 12544
// 12544    eidx[2048]               -> ends 20736
// 24576    pcnt[64*8]               -> ends 26624
// 78080    zb bf16 [2048*128]       -> ends 602368
// 602368   Hb bf16 [3072*1024]      -> ends 6893824

// ------------- fused route+scan (64 blocks, last-block scan) -------------
__global__ __launch_bounds__(256) void routescan_kernel(
    const float* __restrict__ z, __hip_bfloat16* __restrict__ zb,
    int* __restrict__ pcnt, int* __restrict__ eidx, int* __restrict__ done,
    int* __restrict__ ntl, int* __restrict__ texp, int* __restrict__ perm) {
    __shared__ int lcnt[NEXP];          // phase1: local counts; phase2: expert totals
    __shared__ int sp[NRB * NEXP];      // scanner: per-block exclusive prefix
    __shared__ int soff_s[NEXP + 1];
    __shared__ int lastflag;

    int t = threadIdx.x, bid = blockIdx.x;
    if (t < NEXP) lcnt[t] = 0;
    __syncthreads();

    int s = bid * 32 + (t >> 3);          // sample
    int li = t & 7;                       // lane-in-sample
    const float* zp = z + (size_t)s * ZD + li * 16;
    float sum = 0.f;
    union { bf16x8 v8; __hip_bfloat16 h[8]; } u0, u1;
#pragma unroll
    for (int i = 0; i < 4; i++) {
        float4 v = ((const float4*)zp)[i];
        sum += floorf(fabsf(v.x) * 1000.0f) + floorf(fabsf(v.y) * 1000.0f) +
               floorf(fabsf(v.z) * 1000.0f) + floorf(fabsf(v.w) * 1000.0f);
        __hip_bfloat16* dst = (i < 2) ? &u0.h[i * 4] : &u1.h[(i - 2) * 4];
        dst[0] = __float2bfloat16(v.x);
        dst[1] = __float2bfloat16(v.y);
        dst[2] = __float2bfloat16(v.z);
        dst[3] = __float2bfloat16(v.w);
    }
    bf16x8* zo = (bf16x8*)(zb + (size_t)s * ZD + li * 16);
    zo[0] = u0.v8;
    zo[1] = u1.v8;

    sum += __shfl_down(sum, 4);
    sum += __shfl_down(sum, 2);
    sum += __shfl_down(sum, 1);
    if (li == 0) {
        int e = ((int)sum) & 7;
        int lpos = atomicAdd(&lcnt[e], 1);     // lpos < 32: 5 bits
        eidx[s] = e | (lpos << 3);
    }
    __syncthreads();
    if (t < NEXP) pcnt[bid * NEXP + t] = lcnt[t];

    // release writes, then signal completion
    __threadfence();
    if (t == 0) {
        int old = atomicAdd(done, 1);
        lastflag = (((old + 1) & (NRB - 1)) == 0) ? 1 : 0;
    }
    __syncthreads();
    if (!lastflag) return;
    __threadfence();                            // acquire side

    // ---------------- inline scan (this block only) ----------------
    for (int i = t; i < NRB * NEXP; i += 256) sp[i] = pcnt[i];
    __syncthreads();
    if (t < NEXP) {                             // per-expert block prefix
        int run = 0;
        for (int b = 0; b < NRB; ++b) {
            int c = sp[b * NEXP + t];
            sp[b * NEXP + t] = run;
            run += c;
        }
        lcnt[t] = run;                          // expert totals
    }
    __syncthreads();
    if (t == 0) {
        int o = 0;
        for (int e = 0; e < NEXP; e++) {
            soff_s[e] = o;
            o += (lcnt[e] + 127) & ~127;
        }
        soff_s[NEXP] = o;
        *ntl = o / 128;
    }
    __syncthreads();
    int total = soff_s[NEXP];
    for (int r = t; r < total; r += 256) perm[r] = -1;
    for (int tt = t; tt < total / 128; tt += 256) {
        int r = tt * 128, e = 0;
        while (r >= soff_s[e + 1]) e++;
        texp[tt] = e;
    }
    __syncthreads();                            // -1 fill before scatter
    for (int ss = t; ss < BATCH; ss += 256) {
        int pk = eidx[ss];
        int e = pk & 7, lpos = pk >> 3, b = ss >> 5;
        perm[soff_s[e] + sp[b * NEXP + e] + lpos] = ss;
    }
}

// ---------------- gemm1: 64m x 64n, BK=64, K=128 (2 iters) ----------------
// ~608 blocks. All-thread staging; dbuf; 1 raw barrier/iter; XOR-chunk LDS.
__global__ __launch_bounds__(256, 4) void gemm1_fast(
    const __hip_bfloat16* __restrict__ zb, const float* __restrict__ W1,
    const float* __restrict__ b1, const int* __restrict__ ntl,
    const int* __restrict__ texp, const int* __restrict__ perm,
    __hip_bfloat16* __restrict__ H) {
    int mt = blockIdx.y;                 // 64-row tile index
    if (mt >= 2 * (*ntl)) return;
    int e = texp[mt >> 1];
    int n0 = blockIdx.x * 64;

    __shared__ __align__(16) __hip_bfloat16 As[2][64 * 64];   // 2 x 8 KB
    __shared__ __align__(16) __hip_bfloat16 Bs[2][64 * 64];   // 2 x 8 KB

    int tid = threadIdx.x;
    int lane = tid & 63, wave = tid >> 6;
    int cc = lane & 15, q = lane >> 4;
    int mw = (wave >> 1) * 32, nw = (wave & 1) * 32;

    // A staging: thread t covers rows rg and rg+32, k-chunk sc
    int sc = tid & 7, rg = tid >> 3;     // rg 0..31
    int r0 = perm[mt * 64 + rg];      if (r0 < 0) r0 = 0;
    int r1 = perm[mt * 64 + rg + 32]; if (r1 < 0) r1 = 0;
    const __hip_bfloat16* Ap0 = zb + (size_t)r0 * ZD + sc * 8;
    const __hip_bfloat16* Ap1 = zb + (size_t)r1 * ZD + sc * 8;
    int awb = rg * 64 + (sc ^ (rg & 7)) * 8;   // row rg+32 -> +2048, same xor

    // B staging: bkc = k-chunk, 2 n per thread (float2 loads, 64B segments)
    int bkc = tid & 7, bn2 = (tid >> 3) * 2;   // bn2 0..62
    const float* Bgf = W1 + (size_t)e * ZD * HID + (size_t)(bkc * 8) * HID + n0 + bn2;
    int bwb[2];
#pragma unroll
    for (int j = 0; j < 2; j++)
        bwb[j] = ((bn2 + j) * 8 + (bkc ^ ((bn2 + j) & 7))) * 8;

    int A0 = (mw + cc) * 64, B0 = (nw + cc) * 64;
    int X0 = (q ^ (cc & 7)) * 8, X1 = ((4 + q) ^ (cc & 7)) * 8;

    float bias[2];
#pragma unroll
    for (int j = 0; j < 2; j++) bias[j] = b1[(size_t)e * HID + n0 + nw + j * 16 + cc];

    f32x4 zero4 = {0.f, 0.f, 0.f, 0.f};
    f32x4 acc[2][2];
#pragma unroll
    for (int i = 0; i < 2; i++)
#pragma unroll
        for (int j = 0; j < 2; j++) acc[i][j] = zero4;

    bf16x8 ga0 = *(const bf16x8*)Ap0;
    bf16x8 ga1 = *(const bf16x8*)Ap1;
    float2 braw[8];
#pragma unroll
    for (int i = 0; i < 8; i++) braw[i] = *(const float2*)(Bgf + (size_t)i * HID);

#pragma unroll
    for (int it = 0; it < 2; ++it) {
        __hip_bfloat16* Ac = As[it];
        __hip_bfloat16* Bc = Bs[it];
        union { bf16x8 v8; __hip_bfloat16 h[8]; } gbv[2];
#pragma unroll
        for (int i = 0; i < 8; i++) {
            gbv[0].h[i] = __float2bfloat16(braw[i].x);
            gbv[1].h[i] = __float2bfloat16(braw[i].y);
        }
        *(bf16x8*)(Ac + awb) = ga0;
        *(bf16x8*)(Ac + awb + 2048) = ga1;
#pragma unroll
        for (int j = 0; j < 2; j++) *(bf16x8*)(Bc + bwb[j]) = gbv[j].v8;
        if (it == 0) {
            ga0 = *(const bf16x8*)(Ap0 + 64);
            ga1 = *(const bf16x8*)(Ap1 + 64);
#pragma unroll
            for (int i = 0; i < 8; i++)
                braw[i] = *(const float2*)(Bgf + (size_t)(64 + i) * HID);
        }
        BAR_NODRAIN();
#pragma unroll
        for (int kh = 0; kh < 2; ++kh) {
            int X = kh ? X1 : X0;
            bf16x8 af[2], bfr[2];
#pragma unroll
            for (int i = 0; i < 2; i++) af[i] = *(const bf16x8*)(Ac + A0 + i * 1024 + X);
#pragma unroll
            for (int j = 0; j < 2; j++) bfr[j] = *(const bf16x8*)(Bc + B0 + j * 1024 + X);
#pragma unroll
            for (int i = 0; i < 2; i++)
#pragma unroll
                for (int j = 0; j < 2; j++)
                    acc[i][j] = __builtin_amdgcn_mfma_f32_16x16x32_bf16(af[i], bfr[j],
                                                                        acc[i][j], 0, 0, 0);
        }
    }
#pragma unroll
    for (int i = 0; i < 2; i++)
#pragma unroll
        for (int r = 0; r < 4; r++) {
            int m = mw + i * 16 + q * 4 + r;
            __hip_bfloat16* hp = H + (size_t)(mt * 64 + m) * HID + n0 + nw + cc;
#pragma unroll
            for (int j = 0; j < 2; j++)
                hp[j * 16] = __float2bfloat16(fmaxf(acc[i][j][r] + bias[j], 0.f));
        }
}

// ---------------- gemm2: 128m x 128n, BK=64 (round-14 form, CLOSED) ----------------
// Grid (24, MAXTF) = 576 blocks, 2 blocks/CU (64.5 KB LDS). All-thread staging,
// convert deferred past the MFMA phase, ONE raw barrier per phase, 2 LDS
// buffers, distance-2 register prefetch (sets A/B).
__global__ __launch_bounds__(256, 2) void gemm2_fast(
    const __hip_bfloat16* __restrict__ H, const float* __restrict__ W2,
    const float* __restrict__ b2, const int* __restrict__ ntl,
    const int* __restrict__ texp, const int* __restrict__ perm,
    float* __restrict__ out) {
    int mt = blockIdx.y;
    if (mt >= *ntl) return;
    int e = texp[mt];
    int n0 = blockIdx.x * 128;

    __shared__ __align__(16) __hip_bfloat16 As[2][128 * 64];   // 2 x 16 KB
    __shared__ __align__(16) __hip_bfloat16 Bs[2][128 * 64];   // 2 x 16 KB
    __shared__ int rows_s[128];

    int tid = threadIdx.x;
    if (tid < 128) rows_s[tid] = perm[mt * 128 + tid];

    int lane = tid & 63, wave = tid >> 6;
    int cc = lane & 15, q = lane >> 4;
    int mw = (wave >> 1) * 64, nw = (wave & 1) * 64;

    // A staging: thread covers rows sr + p*32 (p=0..3), k-chunk sc
    int sr = tid >> 3, sc = tid & 7;
    int awbase = sr * 64 + (sc ^ (sr & 7)) * 8;     // + p*2048
    const __hip_bfloat16* Ag = H + ((size_t)mt * 128 + sr) * HID + sc * 8;

    // B staging: bkc = k-chunk (8 rows), 4 n per thread (float4)
    int bkc = tid & 7, bn = (tid >> 3) * 4;
    const float* Bgf = W2 + (size_t)e * HID * OUTD + (size_t)(bkc * 8) * OUTD + n0 + bn;
    int bwb[4];
#pragma unroll
    for (int j = 0; j < 4; j++)
        bwb[j] = (bn + j) * 64 + ((bkc ^ ((bn + j) & 7))) * 8;

    int A0 = (mw + cc) * 64, B0 = (nw + cc) * 64;
    int X0 = (q ^ (cc & 7)) * 8, X1 = ((4 + q) ^ (cc & 7)) * 8;

    float bias[4];
#pragma unroll
    for (int j = 0; j < 4; j++) bias[j] = b2[(size_t)e * OUTD + n0 + nw + j * 16 + cc];

    f32x4 zero4 = {0.f, 0.f, 0.f, 0.f};
    f32x4 acc[4][4];
#pragma unroll
    for (int i = 0; i < 4; i++)
#pragma unroll
        for (int j = 0; j < 4; j++) acc[i][j] = zero4;

    // Distance-2 prefetch: set A holds k-block (2*itp), set B holds (2*itp+1).
    bf16x8 gaA[4], gaB[4];
    float4 brA[8], brB[8];
#pragma unroll
    for (int p = 0; p < 4; p++) gaA[p] = *(const bf16x8*)(Ag + (size_t)p * 32 * HID);
#pragma unroll
    for (int i = 0; i < 8; i++) brA[i] = *(const float4*)(Bgf + (size_t)i * OUTD);
#pragma unroll
    for (int p = 0; p < 4; p++) gaB[p] = *(const bf16x8*)(Ag + (size_t)p * 32 * HID + 64);
#pragma unroll
    for (int i = 0; i < 8; i++) brB[i] = *(const float4*)(Bgf + (size_t)(64 + i) * OUTD);

    const int NIT = HID / 64;   // 16 (even)
    for (int itp = 0; itp < NIT / 2; ++itp) {
        int kre = itp * 128;                 // reload bases: even -> kre+128, odd -> kre+192
        bool more = (itp < NIT / 2 - 1);

        // ======== even iter (k-block 2*itp): consume set A, LDS buf 0 ========
        {
            union { bf16x8 v8; __hip_bfloat16 h[8]; } gb[4];
#pragma unroll
            for (int i = 0; i < 8; i++) {
                gb[0].h[i] = __float2bfloat16(brA[i].x);
                gb[1].h[i] = __float2bfloat16(brA[i].y);
                gb[2].h[i] = __float2bfloat16(brA[i].z);
                gb[3].h[i] = __float2bfloat16(brA[i].w);
            }
#pragma unroll
            for (int p = 0; p < 4; p++) *(bf16x8*)(As[0] + awbase + p * 2048) = gaA[p];
#pragma unroll
            for (int j = 0; j < 4; j++) *(bf16x8*)(Bs[0] + bwb[j]) = gb[j].v8;
            if (more) {
#pragma unroll
                for (int p = 0; p < 4; p++)
                    gaA[p] = *(const bf16x8*)(Ag + (size_t)p * 32 * HID + kre + 128);
#pragma unroll
                for (int i = 0; i < 8; i++)
                    brA[i] = *(const float4*)(Bgf + (size_t)(kre + 128 + i) * OUTD);
            }
            BAR_NODRAIN();
#pragma unroll
            for (int kh = 0; kh < 2; ++kh) {
                int X = kh ? X1 : X0;
                bf16x8 af[4], bfr[4];
#pragma unroll
                for (int i = 0; i < 4; i++) af[i] = *(const bf16x8*)(As[0] + A0 + i * 1024 + X);
#pragma unroll
                for (int j = 0; j < 4; j++) bfr[j] = *(const bf16x8*)(Bs[0] + B0 + j * 1024 + X);
#pragma unroll
                for (int i = 0; i < 4; i++)
#pragma unroll
                    for (int j = 0; j < 4; j++)
                        acc[i][j] = __builtin_amdgcn_mfma_f32_16x16x32_bf16(af[i], bfr[j],
                                                                            acc[i][j], 0, 0, 0);
            }
        }

        // ======== odd iter (k-block 2*itp+1): consume set B, LDS buf 1 ========
        {
            union { bf16x8 v8; __hip_bfloat16 h[8]; } gb[4];
#pragma unroll
            for (int i = 0; i < 8; i++) {
                gb[0].h[i] = __float2bfloat16(brB[i].x);
                gb[1].h[i] = __float2bfloat16(brB[i].y);
                gb[2].h[i] = __float2bfloat16(brB[i].z);
                gb[3].h[i] = __float2bfloat16(brB[i].w);
            }
#pragma unroll
            for (int p = 0; p < 4; p++) *(bf16x8*)(As[1] + awbase + p * 2048) = gaB[p];
#pragma unroll
            for (int j = 0; j < 4; j++) *(bf16x8*)(Bs[1] + bwb[j]) = gb[j].v8;
            if (more) {
#pragma unroll
                for (int p = 0; p < 4; p++)
                    gaB[p] = *(const bf16x8*)(Ag + (size_t)p * 32 * HID + kre + 192);
#pragma unroll
                for (int i = 0; i < 8; i++)
                    brB[i] = *(const float4*)(Bgf + (size_t)(kre + 192 + i) * OUTD);
            }
            BAR_NODRAIN();
#pragma unroll
            for (int kh = 0; kh < 2; ++kh) {
                int X = kh ? X1 : X0;
                bf16x8 af[4], bfr[4];
#pragma unroll
                for (int i = 0; i < 4; i++) af[i] = *(const bf16x8*)(As[1] + A0 + i * 1024 + X);
#pragma unroll
                for (int j = 0; j < 4; j++) bfr[j] = *(const bf16x8*)(Bs[1] + B0 + j * 1024 + X);
#pragma unroll
                for (int i = 0; i < 4; i++)
#pragma unroll
                    for (int j = 0; j < 4; j++)
                        acc[i][j] = __builtin_amdgcn_mfma_f32_16x16x32_bf16(af[i], bfr[j],
                                                                            acc[i][j], 0, 0, 0);
            }
        }
    }

#pragma unroll
    for (int i = 0; i < 4; i++)
#pragma unroll
        for (int r = 0; r < 4; r++) {
            int m = mw + i * 16 + q * 4 + r;
            int orow = rows_s[m];
            if (orow >= 0) {
                float* op = out + (size_t)orow * OUTD + n0 + nw + cc;
#pragma unroll
                for (int j = 0; j < 4; j++) op[j * 16] = acc[i][j][r] + bias[j];
            }
        }
}

extern "C" void kernel_launch(void* const* d_in, const int* in_sizes, int n_in,
                              void* d_out, int out_size, void* d_ws, size_t ws_size,
                              hipStream_t stream) {
    const float* z  = (const float*)d_in[0];
    const float* W1 = (const float*)d_in[1];
    const float* b1 = (const float*)d_in[2];
    const float* W2 = (const float*)d_in[3];
    const float* b2 = (const float*)d_in[4];
    float* out = (float*)d_out;

    char* ws = (char*)d_ws;
    int* done   = (int*)ws;
    int* ntl    = (int*)(ws + 64);
    int* texp   = (int*)(ws + 128);
    int* perm   = (int*)(ws + 256);
    int* eidx   = (int*)(ws + 12544);
    int* pcnt   = (int*)(ws + 24576);
    __hip_bfloat16* zb  = (__hip_bfloat16*)(ws + 78080);
    __hip_bfloat16* Hb  = (__hip_bfloat16*)(ws + 602368);

    hipLaunchKernelGGL(routescan_kernel, dim3(NRB), dim3(256), 0, stream,
                       z, zb, pcnt, eidx, done, ntl, texp, perm);
    hipLaunchKernelGGL(gemm1_fast, dim3(HID / 64, 2 * MAXTF), dim3(256), 0, stream,
                       zb, W1, b1, ntl, texp, perm, Hb);
    hipLaunchKernelGGL(gemm2_fast, dim3(OUTD / 128, MAXTF), dim3(256), 0, stream,
                       Hb, W2, b2, ntl, texp, perm, out);
}